// Round 18
// baseline (385.089 us; speedup 1.0000x reference)
//
#include <hip/hip_runtime.h>
#include <hip/hip_fp16.h>

#define N_NODES 100000
#define N_EDGES 1600000
#define F_IN    128
#define F_OUT   32

#define BKT_SHIFT  7
#define BKT_SIZE   128
#define NBKT       782          // ceil(100000/128)
#define BKT_STRIDE 2560         // mean 2046 per bucket, +11 sigma headroom

#define BIN_THREADS 512
#define BIN_TILE    8192
#define EPT         (BIN_TILE / BIN_THREADS)               // 16
#define NTILES      ((N_EDGES + BIN_TILE - 1) / BIN_TILE)  // 196

#define TILE_STRIDE 33   // floats per node row: bank = (dl + c) mod 32 rotation

typedef _Float16 f16x8 __attribute__((ext_vector_type(8)));
typedef float    f32x4 __attribute__((ext_vector_type(4)));

// Bin edges by dst>>7 into 782 buckets. Rank-capture: one LDS atomic per edge
// gives both the histogram and the in-tile rank. [R11-exact]
__global__ __launch_bounds__(BIN_THREADS) void bin_kernel(const int* __restrict__ ei,
                                                          int* __restrict__ gcur,
                                                          unsigned int* __restrict__ binned) {
    __shared__ int cnt[NBKT], gbase[NBKT];
    int t = threadIdx.x;
    for (int b = t; b < NBKT; b += BIN_THREADS) cnt[b] = 0;
    __syncthreads();
    int ebase = blockIdx.x * BIN_TILE;
    unsigned int pk[EPT];
    int rk[EPT];
    short bkt[EPT];
#pragma unroll
    for (int k = 0; k < EPT; ++k) {
        int e = ebase + k * BIN_THREADS + t;
        if (e < N_EDGES) {
            int s = ei[e];
            int d = ei[N_EDGES + e];
            bkt[k] = (short)(d >> BKT_SHIFT);
            pk[k]  = (unsigned)s | ((unsigned)(d & (BKT_SIZE - 1)) << 25);
            rk[k]  = atomicAdd(&cnt[bkt[k]], 1);
        } else {
            bkt[k] = -1;
        }
    }
    __syncthreads();
    for (int b = t; b < NBKT; b += BIN_THREADS)
        if (cnt[b] > 0) gbase[b] = atomicAdd(&gcur[b], cnt[b]);
    __syncthreads();
#pragma unroll
    for (int k = 0; k < EPT; ++k) {
        if (bkt[k] >= 0) {
            int p = gbase[bkt[k]] + rk[k];
            if (p < BKT_STRIDE)
                binned[(size_t)bkt[k] * BKT_STRIDE + p] = pk[k];
        }
    }
}

// Fused: per-bucket degree histogram (-> dinv in LDS) + MFMA matmul for the
// bucket's 128 rows. hs = fp16( (x @ W) * dinv[row] ).  [R11-exact]
#define WH_STRIDE 136   // halfs per W column (272 B -> conflict-free b128)
__global__ __launch_bounds__(512) void matmul_kernel(const float4* __restrict__ x4,
                                                     const float* __restrict__ W,
                                                     const unsigned int* __restrict__ binned,
                                                     const int* __restrict__ gcur,
                                                     __half* __restrict__ hs) {
    __shared__ _Float16 Wh[F_OUT * WH_STRIDE];   // 8.7 KB, [col][k]
    __shared__ int cnt128[BKT_SIZE];
    __shared__ float dinvL[BKT_SIZE];
    int t = threadIdx.x;
    int b = blockIdx.x;

    if (t < BKT_SIZE) cnt128[t] = 0;
    {
        int col = t & 31, kb = (t >> 5) * 8;
        for (int u = 0; u < 8; ++u)
            Wh[col * WH_STRIDE + kb + u] = (_Float16)W[(kb + u) * F_OUT + col];
    }
    __syncthreads();

    int ne = gcur[b];
    if (ne > BKT_STRIDE) ne = BKT_STRIDE;
    const unsigned int* eb = binned + (size_t)b * BKT_STRIDE;
    for (int i = t; i < ne; i += 512)
        atomicAdd(&cnt128[eb[i] >> 25], 1);
    __syncthreads();
    if (t < BKT_SIZE) dinvL[t] = rsqrtf((float)(cnt128[t] + 1));  // +1 self loop
    __syncthreads();

    int w = t >> 6, l = t & 63;
    int lr = l & 15, kg = l >> 4;                // A row lane, k-group
    int row = b * 128 + w * 16 + lr;
    const float4* xr = x4 + (size_t)row * 32;
    bool rok = row < N_NODES;

    f16x8 a[4];
#pragma unroll
    for (int ks = 0; ks < 4; ++ks) {
        float4 v0, v1;
        if (rok) {
            v0 = xr[ks * 8 + kg * 2];
            v1 = xr[ks * 8 + kg * 2 + 1];
        } else {
            v0 = make_float4(0, 0, 0, 0);
            v1 = v0;
        }
        f16x8 av;
        av[0] = (_Float16)v0.x; av[1] = (_Float16)v0.y;
        av[2] = (_Float16)v0.z; av[3] = (_Float16)v0.w;
        av[4] = (_Float16)v1.x; av[5] = (_Float16)v1.y;
        av[6] = (_Float16)v1.z; av[7] = (_Float16)v1.w;
        a[ks] = av;
    }

    f32x4 c0 = {0.f, 0.f, 0.f, 0.f}, c1 = {0.f, 0.f, 0.f, 0.f};
#pragma unroll
    for (int ks = 0; ks < 4; ++ks) {
        f16x8 b0 = *(const f16x8*)&Wh[lr * WH_STRIDE + ks * 32 + kg * 8];
        f16x8 b1 = *(const f16x8*)&Wh[(16 + lr) * WH_STRIDE + ks * 32 + kg * 8];
        c0 = __builtin_amdgcn_mfma_f32_16x16x32_f16(a[ks], b0, c0, 0, 0, 0);
        c1 = __builtin_amdgcn_mfma_f32_16x16x32_f16(a[ks], b1, c1, 0, 0, 0);
    }

    // D layout: col = lane&15, row = (lane>>4)*4 + i   [m89-verified]
    int lrow0 = w * 16 + kg * 4;
#pragma unroll
    for (int i = 0; i < 4; ++i) {
        int orow = b * 128 + lrow0 + i;
        if (orow < N_NODES) {
            float dv = dinvL[lrow0 + i];
            hs[(size_t)orow * F_OUT + lr]      = (__half)(c0[i] * dv);
            hs[(size_t)orow * F_OUT + 16 + lr] = (__half)(c1[i] * dv);
        }
    }
}

// One 512-thread block per bucket. Direct per-edge accumulation into a
// 128x32 fp32 LDS tile via native ds_add_f32 (unsafeAtomicAdd). No sort.
// Tile stride 33 floats -> bank (dl + c) mod 32: ~2-way conflicts.
__global__ __launch_bounds__(512) void aggregate_kernel(const unsigned int* __restrict__ binned,
                                                        const int* __restrict__ gcur,
                                                        const uint2* __restrict__ hs4,
                                                        const float* __restrict__ bias,
                                                        float* __restrict__ out) {
    __shared__ float tile[BKT_SIZE * TILE_STRIDE];   // 16.9 KB
    __shared__ int   cnt[BKT_SIZE];
    int t = threadIdx.x;
    int b = blockIdx.x;
    int ne = gcur[b];
    if (ne > BKT_STRIDE) ne = BKT_STRIDE;
    const unsigned int* eb = binned + (size_t)b * BKT_STRIDE;

    for (int i = t; i < BKT_SIZE * TILE_STRIDE; i += 512) tile[i] = 0.0f;
    if (t < BKT_SIZE) cnt[t] = 0;
    __syncthreads();

    int g = t >> 3, q = t & 7;           // 64 edge-slots x 8 lanes

#define PROC(idx) { \
        unsigned pk = eb[idx]; \
        int s  = (int)(pk & 0x1FFFFFF); \
        int dl = (int)(pk >> 25); \
        uint2 u = hs4[(size_t)s * 8 + q]; \
        float2 f0 = __half22float2(*(__half2*)&u.x); \
        float2 f1 = __half22float2(*(__half2*)&u.y); \
        float* tr = &tile[dl * TILE_STRIDE + q * 4]; \
        unsafeAtomicAdd(tr + 0, f0.x); \
        unsafeAtomicAdd(tr + 1, f0.y); \
        unsafeAtomicAdd(tr + 2, f1.x); \
        unsafeAtomicAdd(tr + 3, f1.y); \
        if (q == 0) atomicAdd(&cnt[dl], 1); \
    }

    int i = g;
    for (; i + 64 < ne; i += 128) {      // 2 edges in flight per lane
        PROC(i)
        PROC(i + 64)
    }
    if (i < ne) PROC(i)
#undef PROC

    __syncthreads();

    // epilogue: 128 nodes x 4 quads of 8 cols
    int n = t >> 2, qq = t & 3;
    int gnode = b * BKT_SIZE + n;
    if (gnode >= N_NODES) return;
    float dv = rsqrtf((float)(cnt[n] + 1));
    const float* tr = &tile[n * TILE_STRIDE + qq * 8];
    uint4 us = *(const uint4*)((const __half*)hs4 + (size_t)gnode * F_OUT + qq * 8);
    float2 s0 = __half22float2(*(__half2*)&us.x);
    float2 s1 = __half22float2(*(__half2*)&us.y);
    float2 s2 = __half22float2(*(__half2*)&us.z);
    float2 s3 = __half22float2(*(__half2*)&us.w);
    float4 bv0 = *(const float4*)&bias[qq * 8];
    float4 bv1 = *(const float4*)&bias[qq * 8 + 4];
    float4 o0, o1;
    o0.x = bv0.x + dv * (tr[0] + s0.x);
    o0.y = bv0.y + dv * (tr[1] + s0.y);
    o0.z = bv0.z + dv * (tr[2] + s1.x);
    o0.w = bv0.w + dv * (tr[3] + s1.y);
    o1.x = bv1.x + dv * (tr[4] + s2.x);
    o1.y = bv1.y + dv * (tr[5] + s2.y);
    o1.z = bv1.z + dv * (tr[6] + s3.x);
    o1.w = bv1.w + dv * (tr[7] + s3.y);
    *(float4*)&out[(size_t)gnode * F_OUT + qq * 8]     = o0;
    *(float4*)&out[(size_t)gnode * F_OUT + qq * 8 + 4] = o1;
}

extern "C" void kernel_launch(void* const* d_in, const int* in_sizes, int n_in,
                              void* d_out, int out_size, void* d_ws, size_t ws_size,
                              hipStream_t stream) {
    const float* x  = (const float*)d_in[0];
    const int*   ei = (const int*)d_in[1];   // int32 on device
    const float* W  = (const float*)d_in[2];
    const float* b  = (const float*)d_in[3];
    float* out = (float*)d_out;

    int*          gcur   = (int*)d_ws;                       // pad to 1024
    unsigned int* binned = (unsigned int*)(gcur + 1024);     // NBKT*BKT_STRIDE ~8 MB
    __half*       hs     = (__half*)(binned + (size_t)NBKT * BKT_STRIDE);  // 6.4 MB

    hipMemsetAsync(gcur, 0, NBKT * sizeof(int), stream);

    bin_kernel<<<NTILES, BIN_THREADS, 0, stream>>>(ei, gcur, binned);

    matmul_kernel<<<NBKT, 512, 0, stream>>>((const float4*)x, W, binned, gcur, hs);

    aggregate_kernel<<<NBKT, 512, 0, stream>>>(binned, gcur, (const uint2*)hs, b, out);
}

// Round 19
// 67.866 us; speedup vs baseline: 5.6743x; 5.6743x over previous
//
#include <hip/hip_runtime.h>
#include <hip/hip_fp16.h>

#define N_NODES 100000
#define N_EDGES 1600000
#define F_IN    128
#define F_OUT   32

#define BKT_SHIFT  7
#define BKT_SIZE   128
#define NBKT       782          // ceil(100000/128)
#define BKT_STRIDE 2560         // mean 2046 per bucket, +11 sigma headroom

#define BIN_THREADS 512
#define BIN_TILE    8192
#define EPT         (BIN_TILE / BIN_THREADS)               // 16
#define NTILES      ((N_EDGES + BIN_TILE - 1) / BIN_TILE)  // 196

#define AGG_SPLIT  4
#define SUB        32           // nodes per aggregate block
#define SUB_STRIDE 768          // mean 512/sub-bucket, +11 sigma headroom

typedef _Float16 f16x8 __attribute__((ext_vector_type(8)));
typedef float    f32x4 __attribute__((ext_vector_type(4)));

__global__ void init_kernel(int* __restrict__ gcur) {
    int i = blockIdx.x * blockDim.x + threadIdx.x;
    if (i < NBKT) gcur[i] = 0;
}

// Bin edges by dst>>7 into 782 buckets. Rank-capture: one LDS atomic per edge
// gives both the histogram and the in-tile rank. [R11-exact]
__global__ __launch_bounds__(BIN_THREADS) void bin_kernel(const int* __restrict__ ei,
                                                          int* __restrict__ gcur,
                                                          unsigned int* __restrict__ binned) {
    __shared__ int cnt[NBKT], gbase[NBKT];
    int t = threadIdx.x;
    for (int b = t; b < NBKT; b += BIN_THREADS) cnt[b] = 0;
    __syncthreads();
    int ebase = blockIdx.x * BIN_TILE;
    unsigned int pk[EPT];
    int rk[EPT];
    short bkt[EPT];
#pragma unroll
    for (int k = 0; k < EPT; ++k) {
        int e = ebase + k * BIN_THREADS + t;
        if (e < N_EDGES) {
            int s = ei[e];
            int d = ei[N_EDGES + e];
            bkt[k] = (short)(d >> BKT_SHIFT);
            pk[k]  = (unsigned)s | ((unsigned)(d & (BKT_SIZE - 1)) << 25);
            rk[k]  = atomicAdd(&cnt[bkt[k]], 1);
        } else {
            bkt[k] = -1;
        }
    }
    __syncthreads();
    for (int b = t; b < NBKT; b += BIN_THREADS)
        if (cnt[b] > 0) gbase[b] = atomicAdd(&gcur[b], cnt[b]);
    __syncthreads();
#pragma unroll
    for (int k = 0; k < EPT; ++k) {
        if (bkt[k] >= 0) {
            int p = gbase[bkt[k]] + rk[k];
            if (p < BKT_STRIDE)
                binned[(size_t)bkt[k] * BKT_STRIDE + p] = pk[k];
        }
    }
}

// Fused: per-bucket degree histogram (-> dinv in LDS) + MFMA matmul for the
// bucket's 128 rows. hs = fp16( (x @ W) * dinv[row] ).  [R11-exact]
#define WH_STRIDE 136   // halfs per W column (272 B -> conflict-free b128)
__global__ __launch_bounds__(512) void matmul_kernel(const float4* __restrict__ x4,
                                                     const float* __restrict__ W,
                                                     const unsigned int* __restrict__ binned,
                                                     const int* __restrict__ gcur,
                                                     __half* __restrict__ hs) {
    __shared__ _Float16 Wh[F_OUT * WH_STRIDE];   // 8.7 KB, [col][k]
    __shared__ int cnt128[BKT_SIZE];
    __shared__ float dinvL[BKT_SIZE];
    int t = threadIdx.x;
    int b = blockIdx.x;

    if (t < BKT_SIZE) cnt128[t] = 0;
    {
        int col = t & 31, kb = (t >> 5) * 8;
        for (int u = 0; u < 8; ++u)
            Wh[col * WH_STRIDE + kb + u] = (_Float16)W[(kb + u) * F_OUT + col];
    }
    __syncthreads();

    int ne = gcur[b];
    if (ne > BKT_STRIDE) ne = BKT_STRIDE;
    const unsigned int* eb = binned + (size_t)b * BKT_STRIDE;
    for (int i = t; i < ne; i += 512)
        atomicAdd(&cnt128[eb[i] >> 25], 1);
    __syncthreads();
    if (t < BKT_SIZE) dinvL[t] = rsqrtf((float)(cnt128[t] + 1));  // +1 self loop
    __syncthreads();

    int w = t >> 6, l = t & 63;
    int lr = l & 15, kg = l >> 4;                // A row lane, k-group
    int row = b * 128 + w * 16 + lr;
    const float4* xr = x4 + (size_t)row * 32;
    bool rok = row < N_NODES;

    f16x8 a[4];
#pragma unroll
    for (int ks = 0; ks < 4; ++ks) {
        float4 v0, v1;
        if (rok) {
            v0 = xr[ks * 8 + kg * 2];
            v1 = xr[ks * 8 + kg * 2 + 1];
        } else {
            v0 = make_float4(0, 0, 0, 0);
            v1 = v0;
        }
        f16x8 av;
        av[0] = (_Float16)v0.x; av[1] = (_Float16)v0.y;
        av[2] = (_Float16)v0.z; av[3] = (_Float16)v0.w;
        av[4] = (_Float16)v1.x; av[5] = (_Float16)v1.y;
        av[6] = (_Float16)v1.z; av[7] = (_Float16)v1.w;
        a[ks] = av;
    }

    f32x4 c0 = {0.f, 0.f, 0.f, 0.f}, c1 = {0.f, 0.f, 0.f, 0.f};
#pragma unroll
    for (int ks = 0; ks < 4; ++ks) {
        f16x8 b0 = *(const f16x8*)&Wh[lr * WH_STRIDE + ks * 32 + kg * 8];
        f16x8 b1 = *(const f16x8*)&Wh[(16 + lr) * WH_STRIDE + ks * 32 + kg * 8];
        c0 = __builtin_amdgcn_mfma_f32_16x16x32_f16(a[ks], b0, c0, 0, 0, 0);
        c1 = __builtin_amdgcn_mfma_f32_16x16x32_f16(a[ks], b1, c1, 0, 0, 0);
    }

    // D layout: col = lane&15, row = (lane>>4)*4 + i   [m89-verified]
    int lrow0 = w * 16 + kg * 4;
#pragma unroll
    for (int i = 0; i < 4; ++i) {
        int orow = b * 128 + lrow0 + i;
        if (orow < N_NODES) {
            float dv = dinvL[lrow0 + i];
            hs[(size_t)orow * F_OUT + lr]      = (__half)(c0[i] * dv);
            hs[(size_t)orow * F_OUT + 16 + lr] = (__half)(c1[i] * dv);
        }
    }
}

__device__ inline void acc4(uint2 u, float& a0, float& a1, float& a2, float& a3) {
    float2 f0 = __half22float2(*(__half2*)&u.x);
    float2 f1 = __half22float2(*(__half2*)&u.y);
    a0 += f0.x; a1 += f0.y; a2 += f1.x; a3 += f1.y;
}

// 4 blocks per bucket, 32 nodes each (grid 3128). Rank-capture counting sort
// with a single-wave shuffle scan (1 barrier instead of ~12), then 8
// lanes/node x 8B gathers, 8-deep unrolled.  [R11 + wave-scan]
__global__ __launch_bounds__(256) void aggregate_kernel(const unsigned int* __restrict__ binned,
                                                        const int* __restrict__ gcur,
                                                        const uint2* __restrict__ hs4,
                                                        const float* __restrict__ bias,
                                                        float* __restrict__ out) {
    __shared__ int cnt[SUB];
    __shared__ int rp[SUB + 1];
    __shared__ int se[SUB_STRIDE];       // 3 KB
    int t = threadIdx.x;
    int b   = blockIdx.x >> 2;           // bucket
    int sub = blockIdx.x & 3;            // quarter of the bucket
    int ne = gcur[b];
    if (ne > BKT_STRIDE) ne = BKT_STRIDE;
    const unsigned int* eb = binned + (size_t)b * BKT_STRIDE;

    if (t < SUB) cnt[t] = 0;
    __syncthreads();

    unsigned pk[10];
    int rk[10];
#pragma unroll
    for (int k = 0; k < 10; ++k) {
        int i = t + k * 256;
        pk[k] = (i < ne) ? eb[i] : 0xFFFFFFFFu;
    }
#pragma unroll
    for (int k = 0; k < 10; ++k) {
        rk[k] = -1;
        if (pk[k] != 0xFFFFFFFFu) {
            int dl = (int)(pk[k] >> 25);
            if ((dl >> 5) == sub) rk[k] = atomicAdd(&cnt[dl & 31], 1);
        }
    }
    __syncthreads();
    // single-wave inclusive scan over the 32 counters (lanes 0-31 of wave 0)
    if (t < SUB) {
        int v = cnt[t];
        int sum = v;
#pragma unroll
        for (int off = 1; off < SUB; off <<= 1) {
            int u = __shfl_up(sum, off, 64);
            if (t >= off) sum += u;
        }
        int ex = sum - v;                // exclusive prefix
        rp[t] = (ex < SUB_STRIDE) ? ex : SUB_STRIDE;
        if (t == SUB - 1) rp[SUB] = (sum > SUB_STRIDE) ? SUB_STRIDE : sum;
    }
    __syncthreads();
#pragma unroll
    for (int k = 0; k < 10; ++k) {
        if (rk[k] >= 0) {
            int dl = (int)(pk[k] >> 25);
            int pos = rp[dl & 31] + rk[k];
            if (pos < SUB_STRIDE) se[pos] = (int)(pk[k] & 0x1FFFFFF);
        }
    }
    __syncthreads();

    int g = t >> 3, j4 = t & 7;          // 32 nodes x 8 lanes (4 cols/lane)
    int gnode = b * BKT_SIZE + sub * SUB + g;
    if (gnode >= N_NODES) return;
    float4 bv = *(const float4*)&bias[j4 * 4];
    int deg = cnt[g];
    int beg = rp[g];
    int end = rp[g + 1];
    if (beg + deg < end) end = beg + deg;
    float a0 = 0.f, a1 = 0.f, a2 = 0.f, a3 = 0.f;
    int p = beg;
    for (; p + 7 < end; p += 8) {        // 8 independent 8B gathers in flight
        uint2 u0 = hs4[(size_t)se[p]     * 8 + j4];
        uint2 u1 = hs4[(size_t)se[p + 1] * 8 + j4];
        uint2 u2 = hs4[(size_t)se[p + 2] * 8 + j4];
        uint2 u3 = hs4[(size_t)se[p + 3] * 8 + j4];
        uint2 u4 = hs4[(size_t)se[p + 4] * 8 + j4];
        uint2 u5 = hs4[(size_t)se[p + 5] * 8 + j4];
        uint2 u6 = hs4[(size_t)se[p + 6] * 8 + j4];
        uint2 u7 = hs4[(size_t)se[p + 7] * 8 + j4];
        acc4(u0, a0, a1, a2, a3); acc4(u1, a0, a1, a2, a3);
        acc4(u2, a0, a1, a2, a3); acc4(u3, a0, a1, a2, a3);
        acc4(u4, a0, a1, a2, a3); acc4(u5, a0, a1, a2, a3);
        acc4(u6, a0, a1, a2, a3); acc4(u7, a0, a1, a2, a3);
    }
    for (; p + 3 < end; p += 4) {
        uint2 u0 = hs4[(size_t)se[p]     * 8 + j4];
        uint2 u1 = hs4[(size_t)se[p + 1] * 8 + j4];
        uint2 u2 = hs4[(size_t)se[p + 2] * 8 + j4];
        uint2 u3 = hs4[(size_t)se[p + 3] * 8 + j4];
        acc4(u0, a0, a1, a2, a3); acc4(u1, a0, a1, a2, a3);
        acc4(u2, a0, a1, a2, a3); acc4(u3, a0, a1, a2, a3);
    }
    for (; p < end; ++p) {
        uint2 u0 = hs4[(size_t)se[p] * 8 + j4];
        acc4(u0, a0, a1, a2, a3);
    }
    float dv = rsqrtf((float)(deg + 1));   // same value matmul folded for src
    uint2 us = hs4[(size_t)gnode * 8 + j4];
    float2 s0 = __half22float2(*(__half2*)&us.x);
    float2 s1 = __half22float2(*(__half2*)&us.y);
    float4 o;
    o.x = bv.x + dv * (a0 + s0.x);
    o.y = bv.y + dv * (a1 + s0.y);
    o.z = bv.z + dv * (a2 + s1.x);
    o.w = bv.w + dv * (a3 + s1.y);
    *(float4*)&out[(size_t)gnode * F_OUT + j4 * 4] = o;
}

extern "C" void kernel_launch(void* const* d_in, const int* in_sizes, int n_in,
                              void* d_out, int out_size, void* d_ws, size_t ws_size,
                              hipStream_t stream) {
    const float* x  = (const float*)d_in[0];
    const int*   ei = (const int*)d_in[1];   // int32 on device
    const float* W  = (const float*)d_in[2];
    const float* b  = (const float*)d_in[3];
    float* out = (float*)d_out;

    int*          gcur   = (int*)d_ws;                       // pad to 1024
    unsigned int* binned = (unsigned int*)(gcur + 1024);     // NBKT*BKT_STRIDE ~8 MB
    __half*       hs     = (__half*)(binned + (size_t)NBKT * BKT_STRIDE);  // 6.4 MB

    init_kernel<<<1, 1024, 0, stream>>>(gcur);

    bin_kernel<<<NTILES, BIN_THREADS, 0, stream>>>(ei, gcur, binned);

    matmul_kernel<<<NBKT, 512, 0, stream>>>((const float4*)x, W, binned, gcur, hs);

    aggregate_kernel<<<NBKT * AGG_SPLIT, 256, 0, stream>>>(binned, gcur, (const uint2*)hs, b, out);
}